// Round 15
// baseline (110.021 us; speedup 1.0000x reference)
//
#include <hip/hip_runtime.h>
#include <math.h>

#define NNODES 50000
#define NEDGES 800000
#define NBKT 196          // buckets of 256 rows
#define BKT_CAP 5120
#define EPB 2048
#define NBA ((NEDGES + EPB - 1) / EPB)    // 391 binA blocks
#define NBN ((NNODES + 127) / 128)        // 391 l0node blocks
#define NBN_A 196                         // l0node blocks in K2
#define NBN_B (NBN - NBN_A)               // 195 l0node blocks in K3

typedef __attribute__((ext_vector_type(8))) short short8;
typedef __attribute__((ext_vector_type(4))) float f32x4;

__device__ inline float bsum64(float v) {
    #pragma unroll
    for (int off = 1; off < 64; off <<= 1) v += __shfl_xor(v, off, 64);
    return v;
}

__device__ inline unsigned packbf2(float a, float b) {
    unsigned ua = __float_as_uint(a);
    unsigned ub = __float_as_uint(b);
    ua = (ua + 0x7fffu + ((ua >> 16) & 1u)) >> 16;
    ub = (ub + 0x7fffu + ((ub >> 16) & 1u)) >> 16;
    return ua | (ub << 16);
}
__device__ inline float bflo(unsigned u) { return __uint_as_float(u << 16); }
__device__ inline float bfhi(unsigned u) { return __uint_as_float(u & 0xffff0000u); }

// ==== K1: W split/swizzle + aug columns (W·attn) + zero cursors ====
__global__ __launch_bounds__(256) void k_prep(const float* __restrict__ W,
                                              const float* __restrict__ attn0,
                                              unsigned short* __restrict__ Whi,
                                              unsigned short* __restrict__ Wlo,
                                              unsigned short* __restrict__ Ahi,
                                              unsigned short* __restrict__ Alo,
                                              int* __restrict__ gcur) {
    int t = threadIdx.x;
    if (blockIdx.x == 64) {
        if (t < NBKT) gcur[t] = 0;
        for (int i = t; i < 2048; i += 256) { Ahi[i] = 0; Alo[i] = 0; }
        __syncthreads();
        // aug: 128 k x 4 cols {ar0,ac0,ar1,ac1}; col c of aug = sum_c W[k,h*64+c]*attn0[...]
        for (int p = t; p < 512; p += 256) {
            int k = p >> 2, col = p & 3;
            int h = col >> 1, rc = col & 1;
            const float* wrow = &W[k * 128 + h * 64];
            const float* arow = &attn0[h * 128 + rc * 64];
            float s = 0.f;
            for (int c = 0; c < 64; c++) s += wrow[c] * arow[c];
            unsigned hb = packbf2(s, 0.f) & 0xffffu;
            float hv = __uint_as_float(hb << 16);
            unsigned lb = packbf2(s - hv, 0.f) & 0xffffu;
            int kc = k >> 5, kk = k & 31, grp = kk >> 3, i = kk & 7;
            int lane = grp * 16 + col;
            int idx = kc * 512 + lane * 8 + i;
            Ahi[idx] = (unsigned short)hb;
            Alo[idx] = (unsigned short)lb;
        }
        return;
    }
    int tid = blockIdx.x * 256 + t;
    int i = tid & 7, lane = (tid >> 3) & 63, ct = (tid >> 9) & 7, kc = tid >> 12;
    int k = kc * 32 + (lane >> 4) * 8 + i;
    int col = ct * 16 + (lane & 15);
    float v = W[k * 128 + col];
    unsigned hb = packbf2(v, 0.f) & 0xffffu;
    float hv = __uint_as_float(hb << 16);
    unsigned lb = packbf2(v - hv, 0.f) & 0xffffu;
    Whi[tid] = (unsigned short)hb;
    Wlo[tid] = (unsigned short)lb;
}

// ---- binA body: bin edges into bucket staging ----
__device__ void binA_body(const int* __restrict__ ei, int* __restrict__ gcur,
                          unsigned* __restrict__ stag, int* shmem) {
    int t = threadIdx.x;
    int* lh = shmem;
    int* lbase = lh + NBKT;
    for (int i = t; i < NBKT; i += 256) lh[i] = 0;
    __syncthreads();
    int e0 = blockIdx.x * EPB;
    int rows[8], cols[8];
    #pragma unroll
    for (int i = 0; i < 8; i++) {
        int e = e0 + i * 256 + t;
        if (e < NEDGES) {
            rows[i] = ei[e];
            cols[i] = ei[NEDGES + e];
            atomicAdd(&lh[rows[i] >> 8], 1);
        }
    }
    __syncthreads();
    for (int i = t; i < NBKT; i += 256) {
        lbase[i] = atomicAdd(&gcur[i], lh[i]);
        lh[i] = 0;
    }
    __syncthreads();
    #pragma unroll
    for (int i = 0; i < 8; i++) {
        int e = e0 + i * 256 + t;
        if (e < NEDGES) {
            int b = rows[i] >> 8;
            int rank = atomicAdd(&lh[b], 1);
            stag[b * BKT_CAP + lbase[b] + rank] =
                ((unsigned)(rows[i] & 255) << 16) | (unsigned)cols[i];
        }
    }
}

// ---- binC body: per-bucket rowptr + row-grouped ecol ----
__device__ void binC_body(int b, const int* __restrict__ gcur,
                          const unsigned* __restrict__ stag,
                          int* __restrict__ rowptr, int* __restrict__ ecol,
                          int* shmem) {
    int t = threadIdx.x;
    int* sh = shmem;
    int* dg = sh + 256;
    int* sc = dg + 256;
    int* cur = sc + 256;
    int* lout = cur + 256;   // BKT_CAP ints
    int gv = (t < NBKT) ? gcur[t] : 0;
    sh[t] = gv;
    __syncthreads();
    #pragma unroll
    for (int off = 1; off < 256; off <<= 1) {
        int u = (t >= off) ? sh[t - off] : 0;
        __syncthreads();
        sh[t] += u;
        __syncthreads();
    }
    int cnt = gcur[b];
    int base = sh[b] - cnt;
    dg[t] = 0;
    __syncthreads();
    for (int i = t; i < cnt; i += 256)
        atomicAdd(&dg[stag[b * BKT_CAP + i] >> 16], 1);
    __syncthreads();
    int v = dg[t];
    sc[t] = v;
    __syncthreads();
    #pragma unroll
    for (int off = 1; off < 256; off <<= 1) {
        int u = (t >= off) ? sc[t - off] : 0;
        __syncthreads();
        sc[t] += u;
        __syncthreads();
    }
    int excl = sc[t] - v;
    int gidx = b * 256 + t;
    if (gidx <= NNODES) rowptr[gidx] = base + excl;
    cur[t] = excl;
    __syncthreads();
    for (int i = t; i < cnt; i += 256) {
        unsigned p = stag[b * BKT_CAP + i];
        int pos = atomicAdd(&cur[p >> 16], 1);
        lout[pos] = (int)(p & 0xffffu);
    }
    __syncthreads();
    for (int i = t; i < cnt; i += 256) ecol[base + i] = lout[i];
}

// ---- l0node body: split-bf16 MFMA GEMM (W + aug in LDS) + h0b pack ----
__device__ void l0node_body(int bid, uint4* shbuf,
                            const float* __restrict__ x,
                            const unsigned short* __restrict__ Whi,
                            const unsigned short* __restrict__ Wlo,
                            const unsigned short* __restrict__ Ahi,
                            const unsigned short* __restrict__ Alo,
                            float* __restrict__ ar, float* __restrict__ ac,
                            unsigned* __restrict__ h0b) {
    int t = threadIdx.x;
    const uint4* WHg = (const uint4*)Whi;
    const uint4* WLg = (const uint4*)Wlo;
    #pragma unroll
    for (int i = 0; i < 8; i++) shbuf[i * 256 + t] = WHg[i * 256 + t];
    #pragma unroll
    for (int i = 0; i < 8; i++) shbuf[2048 + i * 256 + t] = WLg[i * 256 + t];
    shbuf[4096 + t] = ((const uint4*)Ahi)[t];
    shbuf[4352 + t] = ((const uint4*)Alo)[t];
    __syncthreads();

    int w = t >> 6, lane = t & 63;
    int n0 = bid * 128 + w * 32;
    int c16 = lane & 15, grp = lane >> 4;

    f32x4 acc[2][8], accg[2];
    #pragma unroll
    for (int f = 0; f < 2; f++) {
        accg[f] = (f32x4){0.f, 0.f, 0.f, 0.f};
        #pragma unroll
        for (int ct = 0; ct < 8; ct++) acc[f][ct] = (f32x4){0.f, 0.f, 0.f, 0.f};
    }

    for (int kc = 0; kc < 4; kc++) {
        short8 a_h[2], a_l[2];
        #pragma unroll
        for (int f = 0; f < 2; f++) {
            int arow = n0 + f * 16 + c16;
            float xv[8];
            if (arow < NNODES) {
                *(float4*)&xv[0] = *(const float4*)&x[arow * 128 + kc * 32 + grp * 8];
                *(float4*)&xv[4] = *(const float4*)&x[arow * 128 + kc * 32 + grp * 8 + 4];
            } else {
                #pragma unroll
                for (int i = 0; i < 8; i++) xv[i] = 0.f;
            }
            unsigned ah[4], al[4];
            #pragma unroll
            for (int i = 0; i < 4; i++) ah[i] = packbf2(xv[2 * i], xv[2 * i + 1]);
            #pragma unroll
            for (int i = 0; i < 4; i++) {
                float l0 = xv[2 * i] - bflo(ah[i]);
                float l1 = xv[2 * i + 1] - bfhi(ah[i]);
                al[i] = packbf2(l0, l1);
            }
            a_h[f] = *(short8*)ah;
            a_l[f] = *(short8*)al;
        }

        // aug fragment (attn dots as 4 extra columns)
        uint4 ghv = shbuf[4096 + kc * 64 + lane];
        uint4 glv = shbuf[4352 + kc * 64 + lane];
        short8 g_h = *(short8*)&ghv;
        short8 g_l = *(short8*)&glv;
        #pragma unroll
        for (int f = 0; f < 2; f++) {
            accg[f] = __builtin_amdgcn_mfma_f32_16x16x32_bf16(a_h[f], g_h, accg[f], 0, 0, 0);
            accg[f] = __builtin_amdgcn_mfma_f32_16x16x32_bf16(a_h[f], g_l, accg[f], 0, 0, 0);
            accg[f] = __builtin_amdgcn_mfma_f32_16x16x32_bf16(a_l[f], g_h, accg[f], 0, 0, 0);
        }

        #pragma unroll
        for (int ct = 0; ct < 8; ct++) {
            uint4 whv = shbuf[(kc * 8 + ct) * 64 + lane];
            uint4 wlv = shbuf[2048 + (kc * 8 + ct) * 64 + lane];
            short8 b_h = *(short8*)&whv;
            short8 b_l = *(short8*)&wlv;
            #pragma unroll
            for (int f = 0; f < 2; f++) {
                acc[f][ct] = __builtin_amdgcn_mfma_f32_16x16x32_bf16(a_h[f], b_h, acc[f][ct], 0, 0, 0);
                acc[f][ct] = __builtin_amdgcn_mfma_f32_16x16x32_bf16(a_h[f], b_l, acc[f][ct], 0, 0, 0);
                acc[f][ct] = __builtin_amdgcn_mfma_f32_16x16x32_bf16(a_l[f], b_h, acc[f][ct], 0, 0, 0);
            }
        }
    }

    // epilogue: ar/ac direct from aug acc; h0b pack
    #pragma unroll
    for (int f = 0; f < 2; f++) {
        #pragma unroll
        for (int reg = 0; reg < 4; reg++) {
            int n = n0 + f * 16 + grp * 4 + reg;
            if (n < NNODES) {
                if (c16 < 4) {
                    float v = accg[f][reg];
                    if (c16 & 1) ac[n * 2 + (c16 >> 1)] = v;
                    else         ar[n * 2 + (c16 >> 1)] = v;
                }
                #pragma unroll
                for (int ct = 0; ct < 4; ct++)
                    h0b[n * 64 + ct * 16 + c16] = packbf2(acc[f][ct][reg], acc[f][ct + 4][reg]);
            }
        }
    }
}

// ==== K2: binA (0..NBA-1) || l0node bids 0..NBN_A-1 ====
__global__ __launch_bounds__(256) void k_nodeA(const int* __restrict__ ei,
                                               int* __restrict__ gcur,
                                               unsigned* __restrict__ stag,
                                               const float* __restrict__ x,
                                               const unsigned short* __restrict__ Whi,
                                               const unsigned short* __restrict__ Wlo,
                                               const unsigned short* __restrict__ Ahi,
                                               const unsigned short* __restrict__ Alo,
                                               float* __restrict__ ar,
                                               float* __restrict__ ac,
                                               unsigned* __restrict__ h0b) {
    __shared__ uint4 shbuf[4608];   // 72KB
    if (blockIdx.x < NBA) { binA_body(ei, gcur, stag, (int*)shbuf); return; }
    l0node_body(blockIdx.x - NBA, shbuf, x, Whi, Wlo, Ahi, Alo, ar, ac, h0b);
}

// ==== K3: binC (0..NBKT-1) || l0node bids NBN_A..NBN-1 ====
__global__ __launch_bounds__(256) void k_nodeC(const int* __restrict__ gcur,
                                               const unsigned* __restrict__ stag,
                                               int* __restrict__ rowptr,
                                               int* __restrict__ ecol,
                                               const float* __restrict__ x,
                                               const unsigned short* __restrict__ Whi,
                                               const unsigned short* __restrict__ Wlo,
                                               const unsigned short* __restrict__ Ahi,
                                               const unsigned short* __restrict__ Alo,
                                               float* __restrict__ ar,
                                               float* __restrict__ ac,
                                               unsigned* __restrict__ h0b) {
    __shared__ uint4 shbuf[4608];
    if (blockIdx.x < NBKT) { binC_body(blockIdx.x, gcur, stag, rowptr, ecol, (int*)shbuf); return; }
    l0node_body(blockIdx.x - NBKT + NBN_A, shbuf, x, Whi, Wlo, Ahi, Alo, ar, ac, h0b);
}

// ==== K4: layer 0 edge work ====
__global__ __launch_bounds__(256) void k_l0edge(const int* __restrict__ rowptr,
                                                const int* __restrict__ ecol,
                                                const float* __restrict__ ar,
                                                const float* __restrict__ ac,
                                                const unsigned* __restrict__ h0b,
                                                const float* __restrict__ W1,
                                                float* __restrict__ h1) {
    int w = threadIdx.x >> 6, lane = threadIdx.x & 63;
    int n = blockIdx.x * 4 + w;
    if (n >= NNODES) return;
    int beg = rowptr[n];
    int deg = rowptr[n + 1] - beg;
    float arn0 = ar[n * 2], arn1 = ar[n * 2 + 1];
    int esub = lane >> 4;
    int c16 = lane & 15;
    float accA[4] = {0.f, 0.f, 0.f, 0.f};
    float accB[4] = {0.f, 0.f, 0.f, 0.f};
    float s0t = 0.f, s1t = 0.f;
    for (int wb = 0; wb < deg; wb += 64) {
        int cnt = deg - wb; if (cnt > 64) cnt = 64;
        float p0 = 0.f, p1 = 0.f; int colr = 0;
        if (lane < cnt) {
            colr = ecol[beg + wb + lane];
            float2 acv = ((const float2*)ac)[colr];
            float a0 = arn0 + acv.x, a1 = arn1 + acv.y;
            a0 = a0 > 0.f ? a0 : 0.2f * a0;
            a1 = a1 > 0.f ? a1 : 0.2f * a1;
            p0 = __expf(a0); p1 = __expf(a1);
            s0t += p0; s1t += p1;
        }
        int tmax = (cnt + 3) >> 2;
        for (int tt = 0; tt < tmax; tt++) {
            int i4 = tt * 4 + esub;
            int colx = __shfl(colr, i4, 64);
            float q0 = __shfl(p0, i4, 64);
            float q1 = __shfl(p1, i4, 64);
            if (i4 < cnt) {
                const uint4 u = *(const uint4*)(h0b + colx * 64 + c16 * 4);
                accA[0] += q0 * bflo(u.x); accB[0] += q1 * bfhi(u.x);
                accA[1] += q0 * bflo(u.y); accB[1] += q1 * bfhi(u.y);
                accA[2] += q0 * bflo(u.z); accB[2] += q1 * bfhi(u.z);
                accA[3] += q0 * bflo(u.w); accB[3] += q1 * bfhi(u.w);
            }
        }
    }
    float s0 = bsum64(s0t), s1 = bsum64(s1t);
    #pragma unroll
    for (int jj = 0; jj < 4; jj++) {
        accA[jj] += __shfl_xor(accA[jj], 16, 64);
        accA[jj] += __shfl_xor(accA[jj], 32, 64);
        accB[jj] += __shfl_xor(accB[jj], 16, 64);
        accB[jj] += __shfl_xor(accB[jj], 32, 64);
    }
    float si0 = deg ? 0.5f / s0 : 0.f;
    float si1 = deg ? 0.5f / s1 : 0.f;
    float pA = 0.f, pB = 0.f;
    #pragma unroll
    for (int jj = 0; jj < 4; jj++) {
        float o = si0 * accA[jj] + si1 * accB[jj];
        o = o > 0.f ? o : 0.f;   // relu
        float2 wv = ((const float2*)W1)[c16 * 4 + jj];
        pA += o * wv.x; pB += o * wv.y;
    }
    #pragma unroll
    for (int off = 1; off < 16; off <<= 1) {
        pA += __shfl_xor(pA, off, 64);
        pB += __shfl_xor(pB, off, 64);
    }
    if (lane == 0) { h1[n * 2] = pA; h1[n * 2 + 1] = pB; }
}

// ==== K5: layer 1 fused ====
__global__ __launch_bounds__(256) void k_fused1(const int* __restrict__ rowptr,
                                                const int* __restrict__ ecol,
                                                const float* __restrict__ h1,
                                                const float* __restrict__ attn1,
                                                float* __restrict__ dout) {
    int w = threadIdx.x >> 6, lane = threadIdx.x & 63;
    int n = blockIdx.x * 4 + w;
    if (n >= NNODES) return;
    int beg = rowptr[n], end = rowptr[n + 1];
    if (beg == end) { if (lane == 0) dout[n] = 0.f; return; }
    float w01 = attn1[1], w11 = attn1[3];
    float base0 = attn1[0] * h1[n * 2];
    float base1 = attn1[2] * h1[n * 2 + 1];
    float s0 = 0.f, s1 = 0.f, acc0 = 0.f, acc1 = 0.f;
    for (int i = beg + lane; i < end; i += 64) {
        int col = ecol[i];
        float2 v = ((const float2*)h1)[col];
        float a0 = base0 + w01 * v.x;
        float a1 = base1 + w11 * v.y;
        a0 = a0 > 0.f ? a0 : 0.2f * a0;
        a1 = a1 > 0.f ? a1 : 0.2f * a1;
        float p0 = __expf(a0), p1 = __expf(a1);
        s0 += p0; acc0 += p0 * v.x;
        s1 += p1; acc1 += p1 * v.y;
    }
    s0 = bsum64(s0); s1 = bsum64(s1);
    acc0 = bsum64(acc0); acc1 = bsum64(acc1);
    if (lane == 0) dout[n] = 0.5f * (acc0 / s0 + acc1 / s1);
}

extern "C" void kernel_launch(void* const* d_in, const int* in_sizes, int n_in,
                              void* d_out, int out_size, void* d_ws, size_t ws_size,
                              hipStream_t stream) {
    const float* x     = (const float*)d_in[0];
    const int*   ei    = (const int*)d_in[1];
    const float* W0    = (const float*)d_in[2];
    const float* attn0 = (const float*)d_in[3];
    const float* W1    = (const float*)d_in[4];
    const float* attn1 = (const float*)d_in[5];
    float* dout = (float*)d_out;

    float* ws = (float*)d_ws;
    float*          ar     = ws;                             // N*2
    float*          ac     = ar + NNODES * 2;                // N*2
    float*          h1     = ac + NNODES * 2;                // N*2
    unsigned*       h0b    = (unsigned*)(h1 + NNODES * 2);   // N*64
    unsigned short* Whi    = (unsigned short*)(h0b + NNODES * 64); // 128*128
    unsigned short* Wlo    = Whi + 128 * 128;                // 128*128
    unsigned short* Ahi    = Wlo + 128 * 128;                // 2048
    unsigned short* Alo    = Ahi + 2048;                     // 2048
    int*            gcur   = (int*)(Alo + 2048);             // NBKT
    int*            rowptr = gcur + NBKT;                    // N+1
    unsigned*       stag   = (unsigned*)(rowptr + NNODES + 1); // NBKT*BKT_CAP
    int*            ecol   = (int*)(stag + NBKT * BKT_CAP);  // E

    // K1: W split (blocks 0..63) + aug/zero (block 64)
    k_prep<<<65, 256, 0, stream>>>(W0, attn0, Whi, Wlo, Ahi, Alo, gcur);
    // K2: binA (391) || l0node first half (196)
    k_nodeA<<<NBA + NBN_A, 256, 0, stream>>>(ei, gcur, stag, x, Whi, Wlo, Ahi, Alo, ar, ac, h0b);
    // K3: binC (196) || l0node second half (195)
    k_nodeC<<<NBKT + NBN_B, 256, 0, stream>>>(gcur, stag, rowptr, ecol, x, Whi, Wlo, Ahi, Alo, ar, ac, h0b);
    // K4: layer-0 edge work
    k_l0edge<<<(NNODES + 3) / 4, 256, 0, stream>>>(rowptr, ecol, ar, ac, h0b, W1, h1);
    // K5: layer-1
    k_fused1<<<(NNODES + 3) / 4, 256, 0, stream>>>(rowptr, ecol, h1, attn1, dout);
}